// Round 14
// baseline (1086.608 us; speedup 1.0000x reference)
//
#include <hip/hip_runtime.h>
#include <hip/hip_bf16.h>

#define BNC 0.99950037f   // 1/sqrt(1+1e-3), BN eval scale factor
#define GH 400
#define GW 352

typedef __bf16 bf16_t;
typedef __bf16 bf16x8 __attribute__((ext_vector_type(8)));
typedef __bf16 bf16x4 __attribute__((ext_vector_type(4)));
typedef float f32x4 __attribute__((ext_vector_type(4)));

// Bijective XCD-chunked block swizzle (m204): consecutive logical ids land on
// the same XCD's L2 so neighboring tiles share cached rows/weights.
__device__ __forceinline__ int xcd_swz(int orig, int nwg) {
    int q = nwg >> 3, r = nwg & 7;
    int xcd = orig & 7;
    int base = (xcd < r) ? xcd*(q+1) : r*(q+1) + (xcd - r)*q;
    return base + (orig >> 3);
}

// ---------------------------------------------------------------------------
// Winner grid: last voxel index wins for duplicate cells (matches np fancy-set)
// ---------------------------------------------------------------------------
__global__ void k_winner(const int* __restrict__ coors, int* __restrict__ winner, int N) {
    int i = blockIdx.x * 256 + threadIdx.x;
    if (i >= N) return;
    int d = coors[i*4+1], h = coors[i*4+2], w = coors[i*4+3];
    atomicMax(&winner[(d*GH + h)*GW + w], i);
}

// ---------------------------------------------------------------------------
// Weight transpose for conv1/gather: OIDHW -> [tap][ci4][co][4]
// ---------------------------------------------------------------------------
__global__ void k_tr_w(const float* __restrict__ w, float* __restrict__ wt, int CI, int CO) {
    int idx = blockIdx.x * 256 + threadIdx.x;
    int total = 27 * CI * CO;
    if (idx >= total) return;
    int j   = idx & 3;
    int t1  = idx >> 2;
    int co  = t1 % CO;
    int t2  = t1 / CO;
    int ci4 = t2 % (CI/4);
    int tap = t2 / (CI/4);
    int ci  = ci4*4 + j;
    wt[idx] = w[(co*CI + ci)*27 + tap];
}

// Linear-layer weight transpose: wl[u][c] -> WT[c][u]
__global__ void k_tr_lin(const float* __restrict__ wl, float* __restrict__ WT) {
    int idx = blockIdx.x * 256 + threadIdx.x;
    if (idx >= 16384) return;
    int u = idx & 127, c = idx >> 7;
    WT[c*128 + u] = wl[u*128 + c];
}

// Input-activation table: [0:64) gc1*BNC, [64:128) bc1
__global__ void k_prep(const float* __restrict__ g, const float* __restrict__ b,
                       float* __restrict__ out) {
    int i = threadIdx.x;
    if (i < 64)       out[i] = g[i] * BNC;
    else if (i < 128) out[i] = b[i-64];
}

// ---------------------------------------------------------------------------
// Pack 64x64x27 conv weights (OIDHW fp32) into MFMA B-fragment order, split
// into hi/lo bf16. Frag index fb = (s*4 + ct)*64 + lane, s = tap*2 + h.
// ---------------------------------------------------------------------------
__global__ void k_packw(const float* __restrict__ w, bf16_t* __restrict__ wh,
                        bf16_t* __restrict__ wlo) {
    int i = blockIdx.x * 256 + threadIdx.x;    // over 54*4*64 = 13824 frag-lanes
    if (i >= 13824) return;
    int lane = i & 63, ct = (i >> 6) & 3, s = i >> 8;
    int tap = s >> 1, h = s & 1;
    int kg = lane >> 4, wl = lane & 15;
    int co = ct*16 + wl;
    #pragma unroll
    for (int j = 0; j < 8; ++j) {
        int ci = h*32 + kg*8 + j;
        float v = w[(co*64 + ci)*27 + tap];
        bf16_t hi = (bf16_t)v;
        wh[(long)i*8 + j]  = hi;
        wlo[(long)i*8 + j] = (bf16_t)(v - (float)hi);
    }
}

// ---------------------------------------------------------------------------
// VFE: one block (128 thr) per voxel (unchanged from round 11).
// ---------------------------------------------------------------------------
__global__ __launch_bounds__(128) void k_vfe(
    const float* __restrict__ feats, const int* __restrict__ nvox,
    const float* __restrict__ w1, const float* __restrict__ g1g, const float* __restrict__ b1g,
    const float* __restrict__ w2g, const float* __restrict__ g2g, const float* __restrict__ b2g,
    const float* __restrict__ WT, const float* __restrict__ glg, const float* __restrict__ blg,
    float* __restrict__ voxelwise)
{
    __shared__ float F[35*8];
    __shared__ float W1s[16*8];
    __shared__ float SG1[16], SB1[16];
    __shared__ float X1[35*20];
    __shared__ float X2[35*68];
    __shared__ float RED[4*128];
    __shared__ float AGG1[16];
    __shared__ float AGG2[64];
    __shared__ float Y2B[64];
    __shared__ float YB[128];
    __shared__ float MEANS[3];

    int tid = threadIdx.x;
    int vox = blockIdx.x;
    int nv  = nvox[vox];

    const float* fsrc = feats + (long)vox * 140;
    for (int idx = tid; idx < 140; idx += 128) { int t = idx>>2, c = idx&3; F[t*8+c] = fsrc[idx]; }
    if (tid < 35) F[tid*8+7] = 0.f;
    if (tid < 112) { int u = tid/7, c = tid - u*7; W1s[u*8+c] = w1[tid]; }
    if (tid < 16)  { W1s[tid*8+7] = 0.f; SG1[tid] = g1g[tid]*BNC; SB1[tid] = b1g[tid]; }
    __syncthreads();

    if (tid < 3) {
        float s = 0.f;
        for (int t = 0; t < 35; ++t) s += F[t*8 + tid];
        MEANS[tid] = s / (float)nv;
    }
    __syncthreads();
    for (int idx = tid; idx < 105; idx += 128) { int t = idx/3, c = idx - t*3; F[t*8+4+c] = F[t*8+c] - MEANS[c]; }
    __syncthreads();

    {
        const float4* Ff4  = (const float4*)F;
        const float4* W1f4 = (const float4*)W1s;
        for (int idx = tid; idx < 560; idx += 128) {
            int t = idx >> 4, u = idx & 15;
            float4 a0 = Ff4[t*2], a1 = Ff4[t*2+1];
            float4 b0 = W1f4[u*2], b1v = W1f4[u*2+1];
            float a = a0.x*b0.x + a0.y*b0.y + a0.z*b0.z + a0.w*b0.w
                    + a1.x*b1v.x + a1.y*b1v.y + a1.z*b1v.z + a1.w*b1v.w;
            X1[t*20+u] = fmaxf(a*SG1[u] + SB1[u], 0.f);
        }
    }
    __syncthreads();
    if (tid < 16) {
        float m = 0.f;
        for (int t = 0; t < 35; ++t) m = fmaxf(m, X1[t*20+tid]);
        AGG1[tid] = m;
    }
    __syncthreads();
    if (tid < 64) {
        const float4* wsrc = (const float4*)(w2g + tid*32 + 16);
        const float4* A1f4 = (const float4*)AGG1;
        float a = 0.f;
        #pragma unroll
        for (int q = 0; q < 4; ++q) {
            float4 w4 = wsrc[q], x4 = A1f4[q];
            a += x4.x*w4.x + x4.y*w4.y + x4.z*w4.z + x4.w*w4.w;
        }
        Y2B[tid] = a;
    }
    __syncthreads();

    {
        int u = tid & 63, tg = tid >> 6;
        float w2r[16];
        const float4* wsrc = (const float4*)(w2g + u*32);
        #pragma unroll
        for (int q = 0; q < 4; ++q) {
            float4 w4 = wsrc[q];
            w2r[q*4] = w4.x; w2r[q*4+1] = w4.y; w2r[q*4+2] = w4.z; w2r[q*4+3] = w4.w;
        }
        float su = g2g[u]*BNC, bu = b2g[u];
        float yb2 = Y2B[u];
        float lm = (nv < 35) ? fmaxf(bu, 0.f) : 0.f;
        for (int t = tg; t < nv; t += 2) {
            const float4* xr = (const float4*)(X1 + t*20);
            float a = yb2;
            #pragma unroll
            for (int q = 0; q < 4; ++q) {
                float4 x4 = xr[q];
                a += x4.x*w2r[q*4] + x4.y*w2r[q*4+1] + x4.z*w2r[q*4+2] + x4.w*w2r[q*4+3];
            }
            float h = fmaxf(a*su + bu, 0.f);
            X2[t*68 + u] = h;
            lm = fmaxf(lm, h);
        }
        RED[tg*64 + u] = lm;
    }
    __syncthreads();
    if (tid < 64) AGG2[tid] = fmaxf(RED[tid], RED[64+tid]);
    __syncthreads();
    {
        float a = 0.f;
        for (int c = 0; c < 64; ++c) a = fmaf(AGG2[c], WT[(64 + c)*128 + tid], a);
        YB[tid] = a;
    }
    __syncthreads();

    {
        int ug = tid & 31, tg4 = tid >> 5;
        int u0 = ug * 4;
        int kmax = (nv > tg4) ? ((nv - tg4 + 3) >> 2) : 0;
        float acc[9][4];
        #pragma unroll
        for (int k = 0; k < 9; ++k)
            #pragma unroll
            for (int j = 0; j < 4; ++j) acc[k][j] = 0.f;

        const float4* X2f4 = (const float4*)X2;
        const float4* WTf4 = (const float4*)WT;
        for (int c4 = 0; c4 < 16; ++c4) {
            float4 wv[4];
            #pragma unroll
            for (int cc = 0; cc < 4; ++cc)
                wv[cc] = WTf4[(c4*4+cc)*32 + ug];
            #pragma unroll
            for (int k = 0; k < 9; ++k) {
                if (k < kmax) {
                    int t = tg4 + (k << 2);
                    float4 x4 = X2f4[t*17 + c4];
                    #pragma unroll
                    for (int cc = 0; cc < 4; ++cc) {
                        float xs = (cc == 0) ? x4.x : (cc == 1) ? x4.y : (cc == 2) ? x4.z : x4.w;
                        acc[k][0] = fmaf(xs, wv[cc].x, acc[k][0]);
                        acc[k][1] = fmaf(xs, wv[cc].y, acc[k][1]);
                        acc[k][2] = fmaf(xs, wv[cc].z, acc[k][2]);
                        acc[k][3] = fmaf(xs, wv[cc].w, acc[k][3]);
                    }
                }
            }
        }
        float4 g0 = *(const float4*)(glg + u0);
        float4 b0 = *(const float4*)(blg + u0);
        float4 y0 = *(const float4*)(YB + u0);
        float sg[4] = {g0.x*BNC, g0.y*BNC, g0.z*BNC, g0.w*BNC};
        float sb[4] = {b0.x, b0.y, b0.z, b0.w};
        float yv[4] = {y0.x, y0.y, y0.z, y0.w};
        float m[4];
        #pragma unroll
        for (int j = 0; j < 4; ++j) m[j] = 0.f;
        #pragma unroll
        for (int k = 0; k < 9; ++k) {
            if (k < kmax) {
                #pragma unroll
                for (int j = 0; j < 4; ++j)
                    m[j] = fmaxf(m[j], fmaxf((acc[k][j] + yv[j])*sg[j] + sb[j], 0.f));
            }
        }
        #pragma unroll
        for (int j = 0; j < 4; ++j) RED[tg4*128 + u0 + j] = m[j];
    }
    __syncthreads();
    {
        float m = RED[tid];
        #pragma unroll
        for (int r = 1; r < 4; ++r) m = fmaxf(m, RED[r*128 + tid]);
        voxelwise[(long)vox*128 + tid] = m;
    }
}

// ---------------------------------------------------------------------------
// conv1 gather (worklist form) + fused bn1+relu + hi/lo bf16 split on write.
// ---------------------------------------------------------------------------
__global__ __launch_bounds__(256) void k_gat1(
    const float4* __restrict__ voxf4, const int* __restrict__ winner,
    const float4* __restrict__ Wt1, bf16_t* __restrict__ accH,
    bf16_t* __restrict__ accL, const float* __restrict__ gact,
    int h_lo, int AR)
{
    int lg = xcd_swz((int)blockIdx.x, (int)gridDim.x);
    int bx = lg % 11;
    int t1a = lg / 11;
    int r  = t1a % AR;
    int doo = t1a / AR;

    int oh = h_lo + r;
    if ((unsigned)oh >= (unsigned)GH) return;
    int w0 = bx * 32;

    __shared__ int sList[306];
    __shared__ int sCnt;
    __shared__ float4 sF[32][32];

    int t = threadIdx.x;
    if (t == 0) sCnt = 0;
    __syncthreads();
    for (int idx = t; idx < 306; idx += 256) {
        int x = idx % 34, q = idx / 34;
        int kd = q / 3, kh = q - kd*3;
        int dp = doo*2 + kd - 1;
        int hp = oh + kh - 1;
        int wp = w0 - 1 + x;
        if ((unsigned)dp < 10u && (unsigned)hp < (unsigned)GH && (unsigned)wp < (unsigned)GW) {
            int v = winner[(dp*GH + hp)*GW + wp];
            if (v >= 0) {
                int p = atomicAdd(&sCnt, 1);
                sList[p] = (v << 10) | (kd << 8) | (kh << 6) | x;
            }
        }
    }
    __syncthreads();
    int cnt = sCnt;

    int co = t & 63, wv = t >> 6;
    int ibase = wv*8;
    float acc[8];
    #pragma unroll
    for (int i = 0; i < 8; ++i) acc[i] = 0.f;

    for (int c0 = 0; c0 < cnt; c0 += 32) {
        int nch = min(32, cnt - c0);
        __syncthreads();
        for (int idx = t; idx < nch*32; idx += 256) {
            int slot = idx >> 5, c = idx & 31;
            int widx = sList[c0 + slot] >> 10;
            sF[slot][c] = voxf4[(long)widx*32 + c];
        }
        __syncthreads();
        for (int e = 0; e < nch; ++e) {
            int ent = sList[c0 + e];
            int x = ent & 63, kh = (ent >> 6) & 3, kd = (ent >> 8) & 3;
            #pragma unroll
            for (int kw = 0; kw < 3; ++kw) {
                int i = x - kw;
                if (i >= ibase && i < ibase + 8) {      // wave-uniform
                    const float4* wb = Wt1 + (long)(kd*9 + kh*3 + kw)*2048 + co;
                    float a = 0.f;
                    #pragma unroll 4
                    for (int c4 = 0; c4 < 32; ++c4) {
                        float4 wq = wb[c4*64];
                        float4 f4 = sF[e][c4];
                        a += f4.x*wq.x + f4.y*wq.y + f4.z*wq.z + f4.w*wq.w;
                    }
                    int j = i - ibase;
                    #pragma unroll
                    for (int j8 = 0; j8 < 8; ++j8)
                        if (j8 == j) acc[j8] += a;
                }
            }
        }
    }

    float g = gact[co], b = gact[64 + co];
    long rowb = ((long)doo*AR + r)*GW + w0;
    #pragma unroll
    for (int i = 0; i < 8; ++i) {
        float rr = fmaxf(acc[i]*g + b, 0.f);
        bf16_t hi = (bf16_t)rr;
        long idx = (rowb + ibase + i)*64 + co;
        accH[idx] = hi;
        accL[idx] = (bf16_t)(rr - (float)hi);
    }
}

// ---------------------------------------------------------------------------
// Dense conv3d via MFMA 16x16x32 bf16, 3-product hi/lo split.
// FOUR output rows per block, DOUBLE-BUFFERED LDS with one barrier per stage.
// Each plane = 4224 bf16 = 8448 bytes; buffer stride 16896 bytes.
// ---------------------------------------------------------------------------
__global__ __launch_bounds__(256) void k_convm(
    const bf16_t* __restrict__ srcH, const bf16_t* __restrict__ srcL,
    int src_h0, long src_dpitch,
    float* __restrict__ dstF, bf16_t* __restrict__ dstH, bf16_t* __restrict__ dstL,
    int dst_h0, long sC, long sD, long sH,
    const bf16_t* __restrict__ wph, const bf16_t* __restrict__ wpl,
    const float* __restrict__ gout, const float* __restrict__ bout,
    int D_in, int d_stride, int d_pad, int y0, int nrows, int ny)
{
    int lg = xcd_swz((int)blockIdx.x, (int)gridDim.x);
    int bx = lg % 6;
    int t1a = lg / 6;
    int by = t1a % ny;
    int od = t1a / ny;
    int oh0 = y0 + by*4;
    int w0  = bx * 64;

    __shared__ __align__(16) char smem[33792];   // 2 x (sAh 8448B + sAl 8448B)
    float* sOut = (float*)smem;                  // epilogue overlay (17408 B)

    int t = threadIdx.x;
    int lane = t & 63, wv = t >> 6;
    int wl = lane & 15, kg = lane >> 4;
    int mh = wv >> 1, cth = wv & 1;

    // valid-kd contiguous range
    int kdlo = max(0, d_pad - od*d_stride);
    int kdhi = min(3, D_in + d_pad - od*d_stride);
    int nst = (kdhi - kdlo) * 6;

    // per-thread staging slot constants (5 slots x 256 thr >= 1056 elements)
    int s_pl[5], s_gw[5], s_cc[5];
    bool s_in[5];
    #pragma unroll
    for (int k = 0; k < 5; ++k) {
        int c = t + k*256;
        int cl = (c < 1056) ? c : 0;
        int pl = (cl >= 528) ? 1 : 0;
        int cc = cl - pl*528;
        int g = cc / 66, w = cc - g*66;
        int gw = w0 - 1 + w;
        s_pl[k] = pl; s_cc[k] = cc; s_gw[k] = gw*64 + g*8;
        s_in[k] = ((unsigned)gw < (unsigned)GW);
    }
    bool has5 = (t < 32);    // slot 4 only for first 32 threads

    f32x4 acc[4][2][2];                    // [out-row][mt][ct]
    #pragma unroll
    for (int o = 0; o < 4; ++o)
        #pragma unroll
        for (int a = 0; a < 2; ++a)
            #pragma unroll
            for (int b = 0; b < 2; ++b) acc[o][a][b] = (f32x4){0.f, 0.f, 0.f, 0.f};

    const bf16x8* WH = (const bf16x8*)wph;
    const bf16x8* WL = (const bf16x8*)wpl;

    bf16x8 pre[5];
    auto issue = [&](int st) {
        int kdq = st / 6;
        int sr  = st - kdq*6;
        int kd  = kdlo + kdq;
        int dp  = od*d_stride + kd - d_pad;
        int hp  = oh0 - 1 + sr;
        bool vh = ((unsigned)hp < (unsigned)GH);
        long ro = dp*src_dpitch + (long)(hp - src_h0)*(GW*64);
        #pragma unroll
        for (int k = 0; k < 5; ++k) {
            if (k < 4 || has5) {
                if (vh && s_in[k]) {
                    const bf16_t* plane = s_pl[k] ? srcL : srcH;
                    pre[k] = *(const bf16x8*)(plane + ro + s_gw[k]);
                } else {
                    #pragma unroll
                    for (int e = 0; e < 8; ++e) pre[k][e] = (bf16_t)0.f;
                }
            }
        }
    };

    issue(0);
    for (int st = 0; st < nst; ++st) {
        int p = st & 1;
        bf16_t* bAh = (bf16_t*)(smem + p*16896);
        bf16_t* bAl = bAh + 4224;          // +4224 ELEMENTS = +8448 bytes
        // write current stage's prefetched data into buffer p
        #pragma unroll
        for (int k = 0; k < 5; ++k) {
            if (k < 4 || has5) {
                bf16_t* dl = s_pl[k] ? bAl : bAh;
                *(bf16x8*)&dl[s_cc[k]*8] = pre[k];
            }
        }
        if (st + 1 < nst) issue(st + 1);   // next stage's loads fly under compute
        __syncthreads();                   // single barrier per stage

        int kdq = st / 6;
        int sr  = st - kdq*6;
        int kd  = kdlo + kdq;
        #pragma unroll
        for (int h = 0; h < 2; ++h) {
            #pragma unroll
            for (int kw = 0; kw < 3; ++kw) {
                bf16x8 Ah[2], Al[2];
                #pragma unroll
                for (int mt = 0; mt < 2; ++mt) {
                    int ai = ((h*4 + kg)*66 + (mh*2 + mt)*16 + kw + wl)*8;
                    Ah[mt] = *(const bf16x8*)&bAh[ai];
                    Al[mt] = *(const bf16x8*)&bAl[ai];
                }
                #pragma unroll
                for (int oi = 0; oi < 4; ++oi) {
                    int kh = sr - oi;
                    if ((unsigned)kh < 3u) {
                        int s = ((kd*3 + kh)*3 + kw)*2 + h;
                        long fb = (long)(s*4 + cth*2)*64 + lane;
                        bf16x8 B0h = WH[fb],      B0l = WL[fb];
                        bf16x8 B1h = WH[fb + 64], B1l = WL[fb + 64];
                        #pragma unroll
                        for (int mt = 0; mt < 2; ++mt) {
                            acc[oi][mt][0] = __builtin_amdgcn_mfma_f32_16x16x32_bf16(Ah[mt], B0h, acc[oi][mt][0], 0, 0, 0);
                            acc[oi][mt][0] = __builtin_amdgcn_mfma_f32_16x16x32_bf16(Ah[mt], B0l, acc[oi][mt][0], 0, 0, 0);
                            acc[oi][mt][0] = __builtin_amdgcn_mfma_f32_16x16x32_bf16(Al[mt], B0h, acc[oi][mt][0], 0, 0, 0);
                            acc[oi][mt][1] = __builtin_amdgcn_mfma_f32_16x16x32_bf16(Ah[mt], B1h, acc[oi][mt][1], 0, 0, 0);
                            acc[oi][mt][1] = __builtin_amdgcn_mfma_f32_16x16x32_bf16(Ah[mt], B1l, acc[oi][mt][1], 0, 0, 0);
                            acc[oi][mt][1] = __builtin_amdgcn_mfma_f32_16x16x32_bf16(Al[mt], B1h, acc[oi][mt][1], 0, 0, 0);
                        }
                    }
                }
            }
        }
    }

    // ---- epilogue: per output row ----
    float so[2], bo[2];
    #pragma unroll
    for (int ct = 0; ct < 2; ++ct) {
        int co = (cth*2 + ct)*16 + wl;
        so[ct] = gout[co]*BNC; bo[ct] = bout[co];
    }
    if (dstF) {
        // co-major fp32 (conv3 -> d_out)
        #pragma unroll
        for (int oi = 0; oi < 4; ++oi) {
            int oh = oh0 + oi;
            bool rv = ((unsigned)oh < (unsigned)GH) && (by*4 + oi < nrows);
            if (rv) {
                #pragma unroll
                for (int mt = 0; mt < 2; ++mt) {
                    int ow = w0 + (mh*2 + mt)*16 + kg*4;
                    if (ow < GW) {
                        #pragma unroll
                        for (int ct = 0; ct < 2; ++ct) {
                            int co = (cth*2 + ct)*16 + wl;
                            f32x4 r;
                            #pragma unroll
                            for (int e = 0; e < 4; ++e)
                                r[e] = fmaxf(acc[oi][mt][ct][e]*so[ct] + bo[ct], 0.f);
                            *(f32x4*)&dstF[(long)co*sC + (long)od*sD + (long)(oh - dst_h0)*sH + ow] = r;
                        }
                    }
                }
            }
        }
    } else {
        // bf16 hi/lo planes (conv2), bn2+relu fused; rows sequential via LDS
        __syncthreads();      // done reading buffers (sOut overlays them)
        #pragma unroll
        for (int oi = 0; oi < 4; ++oi) {
            int oh = oh0 + oi;
            bool rv = ((unsigned)oh < (unsigned)GH) && (by*4 + oi < nrows);
            if (rv) {          // block-uniform
                #pragma unroll
                for (int mt = 0; mt < 2; ++mt)
                    #pragma unroll
                    for (int ct = 0; ct < 2; ++ct) {
                        int co = (cth*2 + ct)*16 + wl;
                        #pragma unroll
                        for (int e = 0; e < 4; ++e) {
                            int owl = (mh*2 + mt)*16 + kg*4 + e;
                            sOut[owl*68 + co] = fmaxf(acc[oi][mt][ct][e]*so[ct] + bo[ct], 0.f);
                        }
                    }
                __syncthreads();
                for (int f = t; f < 1024; f += 256) {
                    int w = f >> 4, c4 = f & 15;
                    if (w0 + w < GW) {
                        float4 v = *(const float4*)&sOut[w*68 + c4*4];
                        long base = (long)od*sD + (long)(oh - dst_h0)*sH + (long)(w0 + w)*64 + c4*4;
                        bf16_t h0 = (bf16_t)v.x, h1 = (bf16_t)v.y, h2 = (bf16_t)v.z, h3 = (bf16_t)v.w;
                        bf16x4 hv; hv[0]=h0; hv[1]=h1; hv[2]=h2; hv[3]=h3;
                        bf16x4 lv;
                        lv[0]=(bf16_t)(v.x-(float)h0); lv[1]=(bf16_t)(v.y-(float)h1);
                        lv[2]=(bf16_t)(v.z-(float)h2); lv[3]=(bf16_t)(v.w-(float)h3);
                        *(bf16x4*)&dstH[base] = hv;
                        *(bf16x4*)&dstL[base] = lv;
                    }
                }
                __syncthreads();
            }
        }
    }
}

// ---------------------------------------------------------------------------
extern "C" void kernel_launch(void* const* d_in, const int* in_sizes, int n_in,
                              void* d_out, int out_size, void* d_ws, size_t ws_size,
                              hipStream_t stream)
{
    const float* feats = (const float*)d_in[0];
    const int*   nvox  = (const int*)d_in[1];
    const int*   coors = (const int*)d_in[2];
    const float* w1  = (const float*)d_in[4];
    const float* g1  = (const float*)d_in[5];
    const float* b1  = (const float*)d_in[6];
    const float* w2  = (const float*)d_in[7];
    const float* g2  = (const float*)d_in[8];
    const float* b2  = (const float*)d_in[9];
    const float* wl  = (const float*)d_in[10];
    const float* gl  = (const float*)d_in[11];
    const float* bl  = (const float*)d_in[12];
    const float* wc1 = (const float*)d_in[13];
    const float* gc1 = (const float*)d_in[14];
    const float* bc1 = (const float*)d_in[15];
    const float* wc2 = (const float*)d_in[16];
    const float* gc2 = (const float*)d_in[17];
    const float* bc2 = (const float*)d_in[18];
    const float* wc3 = (const float*)d_in[19];
    const float* gc3 = (const float*)d_in[20];
    const float* bc3 = (const float*)d_in[21];

    int N = in_sizes[1];            // 20000 voxels

    auto al = [](size_t b) { return (b + 255) & ~(size_t)255; };

    size_t winB = al((size_t)10*GH*GW*4);
    size_t voxB = al((size_t)N*128*4);
    size_t w1B  = al((size_t)27*128*64*4);
    size_t wlB  = al((size_t)128*128*4);
    size_t wpB  = al((size_t)13824*8*2);   // one packed bf16 weight buffer
    int NS = 20;
    const int cand[8] = {1, 2, 4, 5, 8, 10, 16, 20};
    for (int k = 0; k < 8; ++k) {
        int ns = cand[k], sh = 400/ns, ar = sh + 4, xr = sh + 2;
        size_t tot = 2*al((size_t)5*ar*GW*64*2) + 2*al((size_t)3*xr*GW*64*2)
                   + winB + voxB + w1B + wlB + 4*wpB + 4096;
        if (tot + (1<<16) <= ws_size) { NS = ns; break; }
    }
    int SH = 400/NS, AR = SH + 4, XR = SH + 2;

    char* ws = (char*)d_ws;
    size_t off = 0;
    auto alloc = [&](size_t bytes) -> void* {
        void* p = ws + off; off += al(bytes); return p;
    };
    size_t accB = (size_t)5*AR*GW*64*2;    // one bf16 plane
    size_t actB = (size_t)3*XR*GW*64*2;
    bf16_t* accH   = (bf16_t*)alloc(accB);
    bf16_t* accL   = (bf16_t*)alloc(accB);
    bf16_t* actH   = (bf16_t*)alloc(actB);
    bf16_t* actL   = (bf16_t*)alloc(actB);
    int*    winner = (int*)alloc((size_t)10*GH*GW*4);
    float*  voxw   = (float*)alloc((size_t)N*128*4);
    float*  wt1    = (float*)alloc((size_t)27*128*64*4);
    float*  wtl    = (float*)alloc((size_t)128*128*4);
    bf16_t* wp2h   = (bf16_t*)alloc(wpB);
    bf16_t* wp2l   = (bf16_t*)alloc(wpB);
    bf16_t* wp3h   = (bf16_t*)alloc(wpB);
    bf16_t* wp3l   = (bf16_t*)alloc(wpB);
    float*  gact   = (float*)alloc(256*4);

    hipMemsetAsync(winner, 0xFF, (size_t)10*GH*GW*4, stream);

    k_tr_w<<<(27*128*64 + 255)/256, 256, 0, stream>>>(wc1, wt1, 128, 64);
    k_tr_lin<<<64, 256, 0, stream>>>(wl, wtl);
    k_packw<<<54, 256, 0, stream>>>(wc2, wp2h, wp2l);
    k_packw<<<54, 256, 0, stream>>>(wc3, wp3h, wp3l);
    k_prep<<<1, 256, 0, stream>>>(gc1, bc1, gact);

    k_winner<<<(N + 255)/256, 256, 0, stream>>>(coors, winner, N);
    k_vfe<<<N, 128, 0, stream>>>(feats, nvox, w1, g1, b1, w2, g2, b2,
                                 wtl, gl, bl, voxw);

    for (int s = 0; s < NS; ++s) {
        // conv1 gather + bn1+relu + bf16 split (full coverage, no memset)
        k_gat1<<<11*AR*5, 256, 0, stream>>>(
            (const float4*)voxw, winner, (const float4*)wt1,
            accH, accL, gact, s*SH - 2, AR);
        // conv2 (MFMA, 4 rows/block, dbuf 1-barrier pipeline)
        int ny2 = (SH + 2 + 3)/4;
        k_convm<<<6*ny2*3, 256, 0, stream>>>(
            accH, accL, s*SH - 2, (long)AR*GW*64,
            nullptr, actH, actL, s*SH - 1, 0L, (long)XR*GW*64, (long)GW*64,
            wp2h, wp2l, gc2, bc2,
            5, 1, 0, s*SH - 1, SH + 2, ny2);
        // conv3 (MFMA, 4 rows/block, dbuf 1-barrier pipeline)
        int ny3 = (SH + 3)/4;
        k_convm<<<6*ny3*2, 256, 0, stream>>>(
            actH, actL, s*SH - 1, (long)XR*GW*64,
            (float*)d_out, nullptr, nullptr, 0, (long)2*GH*GW, (long)GH*GW, (long)GW,
            wp3h, wp3l, gc3, bc3,
            3, 2, 1, s*SH, SH, ny3);
    }
}

// Round 15
// 1010.248 us; speedup vs baseline: 1.0756x; 1.0756x over previous
//
#include <hip/hip_runtime.h>
#include <hip/hip_bf16.h>

#define BNC 0.99950037f   // 1/sqrt(1+1e-3), BN eval scale factor
#define GH 400
#define GW 352

typedef __bf16 bf16_t;
typedef __bf16 bf16x8 __attribute__((ext_vector_type(8)));
typedef __bf16 bf16x4 __attribute__((ext_vector_type(4)));
typedef float f32x4 __attribute__((ext_vector_type(4)));

// Bijective XCD-chunked block swizzle (m204): consecutive logical ids land on
// the same XCD's L2 so neighboring tiles share cached rows/weights.
__device__ __forceinline__ int xcd_swz(int orig, int nwg) {
    int q = nwg >> 3, r = nwg & 7;
    int xcd = orig & 7;
    int base = (xcd < r) ? xcd*(q+1) : r*(q+1) + (xcd - r)*q;
    return base + (orig >> 3);
}

// ---------------------------------------------------------------------------
// Winner grid: last voxel index wins for duplicate cells (matches np fancy-set)
// ---------------------------------------------------------------------------
__global__ void k_winner(const int* __restrict__ coors, int* __restrict__ winner, int N) {
    int i = blockIdx.x * 256 + threadIdx.x;
    if (i >= N) return;
    int d = coors[i*4+1], h = coors[i*4+2], w = coors[i*4+3];
    atomicMax(&winner[(d*GH + h)*GW + w], i);
}

// ---------------------------------------------------------------------------
// Merged weight-prep kernel (replaces 5 tiny launches):
//  seg0 blocks [0,864):    wc1 OIDHW -> wt1 [tap][ci4][co][4]
//  seg1 [864,928):         wl[u][c] -> wtl[c][u]
//  seg2 [928,982):         packw wc2 -> wp2h/wp2l
//  seg3 [982,1036):        packw wc3 -> wp3h/wp3l
//  seg4 [1036]:            gact table
// ---------------------------------------------------------------------------
__device__ __forceinline__ void packw_one(const float* __restrict__ w,
                                          bf16_t* __restrict__ wh,
                                          bf16_t* __restrict__ wlo, int i) {
    if (i >= 13824) return;
    int lane = i & 63, ct = (i >> 6) & 3, s = i >> 8;
    int tap = s >> 1, h = s & 1;
    int kg = lane >> 4, wl = lane & 15;
    int co = ct*16 + wl;
    #pragma unroll
    for (int j = 0; j < 8; ++j) {
        int ci = h*32 + kg*8 + j;
        float v = w[(co*64 + ci)*27 + tap];
        bf16_t hi = (bf16_t)v;
        wh[(long)i*8 + j]  = hi;
        wlo[(long)i*8 + j] = (bf16_t)(v - (float)hi);
    }
}

__global__ void k_prep_all(
    const float* __restrict__ wc1, float* __restrict__ wt1,
    const float* __restrict__ wl,  float* __restrict__ wtl,
    const float* __restrict__ wc2, bf16_t* __restrict__ wp2h, bf16_t* __restrict__ wp2l,
    const float* __restrict__ wc3, bf16_t* __restrict__ wp3h, bf16_t* __restrict__ wp3l,
    const float* __restrict__ gc1, const float* __restrict__ bc1,
    float* __restrict__ gact)
{
    int b = blockIdx.x;
    int t = threadIdx.x;
    if (b < 864) {
        int idx = b*256 + t;                   // 27*128*64 = 221184
        if (idx < 221184) {
            int j   = idx & 3;
            int t1  = idx >> 2;
            int co  = t1 & 63;
            int t2  = t1 >> 6;
            int ci4 = t2 & 31;
            int tap = t2 >> 5;
            int ci  = ci4*4 + j;
            wt1[idx] = wc1[(co*128 + ci)*27 + tap];
        }
    } else if (b < 928) {
        int idx = (b - 864)*256 + t;           // 16384
        if (idx < 16384) {
            int u = idx & 127, c = idx >> 7;
            wtl[c*128 + u] = wl[u*128 + c];
        }
    } else if (b < 982) {
        packw_one(wc2, wp2h, wp2l, (b - 928)*256 + t);
    } else if (b < 1036) {
        packw_one(wc3, wp3h, wp3l, (b - 982)*256 + t);
    } else {
        if (t < 64)       gact[t] = gc1[t] * BNC;
        else if (t < 128) gact[t] = bc1[t-64];
    }
}

// ---------------------------------------------------------------------------
// VFE: one block (128 thr) per voxel (r11/r12 structure, unchanged).
// ---------------------------------------------------------------------------
__global__ __launch_bounds__(128) void k_vfe(
    const float* __restrict__ feats, const int* __restrict__ nvox,
    const float* __restrict__ w1, const float* __restrict__ g1g, const float* __restrict__ b1g,
    const float* __restrict__ w2g, const float* __restrict__ g2g, const float* __restrict__ b2g,
    const float* __restrict__ WT, const float* __restrict__ glg, const float* __restrict__ blg,
    float* __restrict__ voxelwise)
{
    __shared__ float F[35*8];
    __shared__ float W1s[16*8];
    __shared__ float SG1[16], SB1[16];
    __shared__ float X1[35*20];
    __shared__ float X2[35*68];
    __shared__ float RED[4*128];
    __shared__ float AGG1[16];
    __shared__ float AGG2[64];
    __shared__ float Y2B[64];
    __shared__ float YB[128];
    __shared__ float MEANS[3];

    int tid = threadIdx.x;
    int vox = blockIdx.x;
    int nv  = nvox[vox];

    const float* fsrc = feats + (long)vox * 140;
    for (int idx = tid; idx < 140; idx += 128) { int t = idx>>2, c = idx&3; F[t*8+c] = fsrc[idx]; }
    if (tid < 35) F[tid*8+7] = 0.f;
    if (tid < 112) { int u = tid/7, c = tid - u*7; W1s[u*8+c] = w1[tid]; }
    if (tid < 16)  { W1s[tid*8+7] = 0.f; SG1[tid] = g1g[tid]*BNC; SB1[tid] = b1g[tid]; }
    __syncthreads();

    if (tid < 3) {
        float s = 0.f;
        for (int t = 0; t < 35; ++t) s += F[t*8 + tid];
        MEANS[tid] = s / (float)nv;
    }
    __syncthreads();
    for (int idx = tid; idx < 105; idx += 128) { int t = idx/3, c = idx - t*3; F[t*8+4+c] = F[t*8+c] - MEANS[c]; }
    __syncthreads();

    {
        const float4* Ff4  = (const float4*)F;
        const float4* W1f4 = (const float4*)W1s;
        for (int idx = tid; idx < 560; idx += 128) {
            int t = idx >> 4, u = idx & 15;
            float4 a0 = Ff4[t*2], a1 = Ff4[t*2+1];
            float4 b0 = W1f4[u*2], b1v = W1f4[u*2+1];
            float a = a0.x*b0.x + a0.y*b0.y + a0.z*b0.z + a0.w*b0.w
                    + a1.x*b1v.x + a1.y*b1v.y + a1.z*b1v.z + a1.w*b1v.w;
            X1[t*20+u] = fmaxf(a*SG1[u] + SB1[u], 0.f);
        }
    }
    __syncthreads();
    if (tid < 16) {
        float m = 0.f;
        for (int t = 0; t < 35; ++t) m = fmaxf(m, X1[t*20+tid]);
        AGG1[tid] = m;
    }
    __syncthreads();
    if (tid < 64) {
        const float4* wsrc = (const float4*)(w2g + tid*32 + 16);
        const float4* A1f4 = (const float4*)AGG1;
        float a = 0.f;
        #pragma unroll
        for (int q = 0; q < 4; ++q) {
            float4 w4 = wsrc[q], x4 = A1f4[q];
            a += x4.x*w4.x + x4.y*w4.y + x4.z*w4.z + x4.w*w4.w;
        }
        Y2B[tid] = a;
    }
    __syncthreads();

    {
        int u = tid & 63, tg = tid >> 6;
        float w2r[16];
        const float4* wsrc = (const float4*)(w2g + u*32);
        #pragma unroll
        for (int q = 0; q < 4; ++q) {
            float4 w4 = wsrc[q];
            w2r[q*4] = w4.x; w2r[q*4+1] = w4.y; w2r[q*4+2] = w4.z; w2r[q*4+3] = w4.w;
        }
        float su = g2g[u]*BNC, bu = b2g[u];
        float yb2 = Y2B[u];
        float lm = (nv < 35) ? fmaxf(bu, 0.f) : 0.f;
        for (int t = tg; t < nv; t += 2) {
            const float4* xr = (const float4*)(X1 + t*20);
            float a = yb2;
            #pragma unroll
            for (int q = 0; q < 4; ++q) {
                float4 x4 = xr[q];
                a += x4.x*w2r[q*4] + x4.y*w2r[q*4+1] + x4.z*w2r[q*4+2] + x4.w*w2r[q*4+3];
            }
            float h = fmaxf(a*su + bu, 0.f);
            X2[t*68 + u] = h;
            lm = fmaxf(lm, h);
        }
        RED[tg*64 + u] = lm;
    }
    __syncthreads();
    if (tid < 64) AGG2[tid] = fmaxf(RED[tid], RED[64+tid]);
    __syncthreads();
    {
        float a = 0.f;
        for (int c = 0; c < 64; ++c) a = fmaf(AGG2[c], WT[(64 + c)*128 + tid], a);
        YB[tid] = a;
    }
    __syncthreads();

    {
        int ug = tid & 31, tg4 = tid >> 5;
        int u0 = ug * 4;
        int kmax = (nv > tg4) ? ((nv - tg4 + 3) >> 2) : 0;
        float acc[9][4];
        #pragma unroll
        for (int k = 0; k < 9; ++k)
            #pragma unroll
            for (int j = 0; j < 4; ++j) acc[k][j] = 0.f;

        const float4* X2f4 = (const float4*)X2;
        const float4* WTf4 = (const float4*)WT;
        for (int c4 = 0; c4 < 16; ++c4) {
            float4 wv[4];
            #pragma unroll
            for (int cc = 0; cc < 4; ++cc)
                wv[cc] = WTf4[(c4*4+cc)*32 + ug];
            #pragma unroll
            for (int k = 0; k < 9; ++k) {
                if (k < kmax) {
                    int t = tg4 + (k << 2);
                    float4 x4 = X2f4[t*17 + c4];
                    #pragma unroll
                    for (int cc = 0; cc < 4; ++cc) {
                        float xs = (cc == 0) ? x4.x : (cc == 1) ? x4.y : (cc == 2) ? x4.z : x4.w;
                        acc[k][0] = fmaf(xs, wv[cc].x, acc[k][0]);
                        acc[k][1] = fmaf(xs, wv[cc].y, acc[k][1]);
                        acc[k][2] = fmaf(xs, wv[cc].z, acc[k][2]);
                        acc[k][3] = fmaf(xs, wv[cc].w, acc[k][3]);
                    }
                }
            }
        }
        float4 g0 = *(const float4*)(glg + u0);
        float4 b0 = *(const float4*)(blg + u0);
        float4 y0 = *(const float4*)(YB + u0);
        float sg[4] = {g0.x*BNC, g0.y*BNC, g0.z*BNC, g0.w*BNC};
        float sb[4] = {b0.x, b0.y, b0.z, b0.w};
        float yv[4] = {y0.x, y0.y, y0.z, y0.w};
        float m[4];
        #pragma unroll
        for (int j = 0; j < 4; ++j) m[j] = 0.f;
        #pragma unroll
        for (int k = 0; k < 9; ++k) {
            if (k < kmax) {
                #pragma unroll
                for (int j = 0; j < 4; ++j)
                    m[j] = fmaxf(m[j], fmaxf((acc[k][j] + yv[j])*sg[j] + sb[j], 0.f));
            }
        }
        #pragma unroll
        for (int j = 0; j < 4; ++j) RED[tg4*128 + u0 + j] = m[j];
    }
    __syncthreads();
    {
        float m = RED[tid];
        #pragma unroll
        for (int r = 1; r < 4; ++r) m = fmaxf(m, RED[r*128 + tid]);
        voxelwise[(long)vox*128 + tid] = m;
    }
}

// ---------------------------------------------------------------------------
// conv1 gather (worklist form) + fused bn1+relu + hi/lo bf16 split on write.
// ---------------------------------------------------------------------------
__global__ __launch_bounds__(256) void k_gat1(
    const float4* __restrict__ voxf4, const int* __restrict__ winner,
    const float4* __restrict__ Wt1, bf16_t* __restrict__ accH,
    bf16_t* __restrict__ accL, const float* __restrict__ gact,
    int h_lo, int AR)
{
    int lg = xcd_swz((int)blockIdx.x, (int)gridDim.x);
    int bx = lg % 11;
    int t1a = lg / 11;
    int r  = t1a % AR;
    int doo = t1a / AR;

    int oh = h_lo + r;
    if ((unsigned)oh >= (unsigned)GH) return;
    int w0 = bx * 32;

    __shared__ int sList[306];
    __shared__ int sCnt;
    __shared__ float4 sF[32][32];

    int t = threadIdx.x;
    if (t == 0) sCnt = 0;
    __syncthreads();
    for (int idx = t; idx < 306; idx += 256) {
        int x = idx % 34, q = idx / 34;
        int kd = q / 3, kh = q - kd*3;
        int dp = doo*2 + kd - 1;
        int hp = oh + kh - 1;
        int wp = w0 - 1 + x;
        if ((unsigned)dp < 10u && (unsigned)hp < (unsigned)GH && (unsigned)wp < (unsigned)GW) {
            int v = winner[(dp*GH + hp)*GW + wp];
            if (v >= 0) {
                int p = atomicAdd(&sCnt, 1);
                sList[p] = (v << 10) | (kd << 8) | (kh << 6) | x;
            }
        }
    }
    __syncthreads();
    int cnt = sCnt;

    int co = t & 63, wv = t >> 6;
    int ibase = wv*8;
    float acc[8];
    #pragma unroll
    for (int i = 0; i < 8; ++i) acc[i] = 0.f;

    for (int c0 = 0; c0 < cnt; c0 += 32) {
        int nch = min(32, cnt - c0);
        __syncthreads();
        for (int idx = t; idx < nch*32; idx += 256) {
            int slot = idx >> 5, c = idx & 31;
            int widx = sList[c0 + slot] >> 10;
            sF[slot][c] = voxf4[(long)widx*32 + c];
        }
        __syncthreads();
        for (int e = 0; e < nch; ++e) {
            int ent = sList[c0 + e];
            int x = ent & 63, kh = (ent >> 6) & 3, kd = (ent >> 8) & 3;
            #pragma unroll
            for (int kw = 0; kw < 3; ++kw) {
                int i = x - kw;
                if (i >= ibase && i < ibase + 8) {      // wave-uniform
                    const float4* wb = Wt1 + (long)(kd*9 + kh*3 + kw)*2048 + co;
                    float a = 0.f;
                    #pragma unroll 4
                    for (int c4 = 0; c4 < 32; ++c4) {
                        float4 wq = wb[c4*64];
                        float4 f4 = sF[e][c4];
                        a += f4.x*wq.x + f4.y*wq.y + f4.z*wq.z + f4.w*wq.w;
                    }
                    int j = i - ibase;
                    #pragma unroll
                    for (int j8 = 0; j8 < 8; ++j8)
                        if (j8 == j) acc[j8] += a;
                }
            }
        }
    }

    float g = gact[co], b = gact[64 + co];
    long rowb = ((long)doo*AR + r)*GW + w0;
    #pragma unroll
    for (int i = 0; i < 8; ++i) {
        float rr = fmaxf(acc[i]*g + b, 0.f);
        bf16_t hi = (bf16_t)rr;
        long idx = (rowb + ibase + i)*64 + co;
        accH[idx] = hi;
        accL[idx] = (bf16_t)(rr - (float)hi);
    }
}

// ---------------------------------------------------------------------------
// Dense conv3d via MFMA 16x16x32 bf16, 3-product hi/lo split. 2 output rows
// per block. T14 async-STAGE: stage loads for phase st+1 issue right after
// phase st's LDS write -> HBM latency hides under MFMA compute. 1D grid with
// XCD-chunked swizzle for L2 row/weight reuse. (r12 proven version.)
// ---------------------------------------------------------------------------
__global__ __launch_bounds__(256) void k_convm(
    const bf16_t* __restrict__ srcH, const bf16_t* __restrict__ srcL,
    int src_h0, long src_dpitch,
    float* __restrict__ dstF, bf16_t* __restrict__ dstH, bf16_t* __restrict__ dstL,
    int dst_h0, long sC, long sD, long sH,
    const bf16_t* __restrict__ wph, const bf16_t* __restrict__ wpl,
    const float* __restrict__ gout, const float* __restrict__ bout,
    int D_in, int d_stride, int d_pad, int y0, int nrows, int ny)
{
    int lg = xcd_swz((int)blockIdx.x, (int)gridDim.x);
    int bx = lg % 6;
    int t1a = lg / 6;
    int by = t1a % ny;
    int od = t1a / ny;
    int oh0 = y0 + by*2;
    int w0  = bx * 64;

    __shared__ __align__(16) char smem[17408];
    bf16_t* sAh = (bf16_t*)smem;           // [8 g][66 w][8 bf16] = 8448 B
    bf16_t* sAl = (bf16_t*)(smem + 8448);  // 8448 B
    float*  sOut = (float*)smem;           // [64 w][68] fp32 = 17408 B (overlay)

    int t = threadIdx.x;
    int lane = t & 63, wv = t >> 6;
    int wl = lane & 15, kg = lane >> 4;
    int mh = wv >> 1, cth = wv & 1;

    // valid-kd contiguous range
    int kdlo = max(0, d_pad - od*d_stride);
    int kdhi = min(3, D_in + d_pad - od*d_stride);
    int nst = (kdhi - kdlo) * 4;

    // per-thread staging slot constants (5 slots x 256 thr >= 1056 elements)
    int s_pl[5], s_gw[5], s_cc[5];
    bool s_in[5];
    #pragma unroll
    for (int k = 0; k < 5; ++k) {
        int c = t + k*256;
        int cl = (c < 1056) ? c : 0;
        int pl = (cl >= 528) ? 1 : 0;
        int cc = cl - pl*528;
        int g = cc / 66, w = cc - g*66;
        int gw = w0 - 1 + w;
        s_pl[k] = pl; s_cc[k] = cc; s_gw[k] = gw*64 + g*8;
        s_in[k] = ((unsigned)gw < (unsigned)GW);
    }
    bool has5 = (t < 32);    // slot 4 only for first 32 threads

    f32x4 acc[2][2][2];                    // [out-row][mt][ct]
    #pragma unroll
    for (int o = 0; o < 2; ++o)
        #pragma unroll
        for (int a = 0; a < 2; ++a)
            #pragma unroll
            for (int b = 0; b < 2; ++b) acc[o][a][b] = (f32x4){0.f, 0.f, 0.f, 0.f};

    const bf16x8* WH = (const bf16x8*)wph;
    const bf16x8* WL = (const bf16x8*)wpl;

    bf16x8 pre[5];
    auto issue = [&](int st) {
        int kd = kdlo + (st >> 2);
        int dp = od*d_stride + kd - d_pad;
        int sr = st & 3;
        int hp = oh0 - 1 + sr;
        bool vh = ((unsigned)hp < (unsigned)GH);
        long ro = dp*src_dpitch + (long)(hp - src_h0)*(GW*64);
        #pragma unroll
        for (int k = 0; k < 5; ++k) {
            if (k < 4 || has5) {
                if (vh && s_in[k]) {
                    const bf16_t* plane = s_pl[k] ? srcL : srcH;
                    pre[k] = *(const bf16x8*)(plane + ro + s_gw[k]);
                } else {
                    #pragma unroll
                    for (int e = 0; e < 8; ++e) pre[k][e] = (bf16_t)0.f;
                }
            }
        }
    };

    issue(0);
    for (int st = 0; st < nst; ++st) {
        __syncthreads();                   // prior phase readers done
        #pragma unroll
        for (int k = 0; k < 5; ++k) {
            if (k < 4 || has5) {
                bf16_t* dl = s_pl[k] ? sAl : sAh;
                *(bf16x8*)&dl[s_cc[k]*8] = pre[k];
            }
        }
        if (st + 1 < nst) issue(st + 1);   // loads fly during compute
        __syncthreads();

        int kd = kdlo + (st >> 2);
        int sr = st & 3;
        #pragma unroll
        for (int h = 0; h < 2; ++h) {
            #pragma unroll
            for (int kw = 0; kw < 3; ++kw) {
                bf16x8 Ah[2], Al[2];
                #pragma unroll
                for (int mt = 0; mt < 2; ++mt) {
                    int ai = ((h*4 + kg)*66 + (mh*2 + mt)*16 + kw + wl)*8;
                    Ah[mt] = *(const bf16x8*)&sAh[ai];
                    Al[mt] = *(const bf16x8*)&sAl[ai];
                }
                #pragma unroll
                for (int oi = 0; oi < 2; ++oi) {
                    int kh = sr - oi;
                    if ((unsigned)kh < 3u) {
                        int s = ((kd*3 + kh)*3 + kw)*2 + h;
                        long fb = (long)(s*4 + cth*2)*64 + lane;
                        bf16x8 B0h = WH[fb],      B0l = WL[fb];
                        bf16x8 B1h = WH[fb + 64], B1l = WL[fb + 64];
                        #pragma unroll
                        for (int mt = 0; mt < 2; ++mt) {
                            acc[oi][mt][0] = __builtin_amdgcn_mfma_f32_16x16x32_bf16(Ah[mt], B0h, acc[oi][mt][0], 0, 0, 0);
                            acc[oi][mt][0] = __builtin_amdgcn_mfma_f32_16x16x32_bf16(Ah[mt], B0l, acc[oi][mt][0], 0, 0, 0);
                            acc[oi][mt][0] = __builtin_amdgcn_mfma_f32_16x16x32_bf16(Al[mt], B0h, acc[oi][mt][0], 0, 0, 0);
                            acc[oi][mt][1] = __builtin_amdgcn_mfma_f32_16x16x32_bf16(Ah[mt], B1h, acc[oi][mt][1], 0, 0, 0);
                            acc[oi][mt][1] = __builtin_amdgcn_mfma_f32_16x16x32_bf16(Ah[mt], B1l, acc[oi][mt][1], 0, 0, 0);
                            acc[oi][mt][1] = __builtin_amdgcn_mfma_f32_16x16x32_bf16(Al[mt], B1h, acc[oi][mt][1], 0, 0, 0);
                        }
                    }
                }
            }
        }
    }

    // ---- epilogue: per output row ----
    float so[2], bo[2];
    #pragma unroll
    for (int ct = 0; ct < 2; ++ct) {
        int co = (cth*2 + ct)*16 + wl;
        so[ct] = gout[co]*BNC; bo[ct] = bout[co];
    }
    if (dstF) {
        // co-major fp32 (conv3 -> d_out)
        #pragma unroll
        for (int oi = 0; oi < 2; ++oi) {
            int oh = oh0 + oi;
            bool rv = ((unsigned)oh < (unsigned)GH) && (by*2 + oi < nrows);
            if (rv) {
                #pragma unroll
                for (int mt = 0; mt < 2; ++mt) {
                    int ow = w0 + (mh*2 + mt)*16 + kg*4;
                    if (ow < GW) {
                        #pragma unroll
                        for (int ct = 0; ct < 2; ++ct) {
                            int co = (cth*2 + ct)*16 + wl;
                            f32x4 r;
                            #pragma unroll
                            for (int e = 0; e < 4; ++e)
                                r[e] = fmaxf(acc[oi][mt][ct][e]*so[ct] + bo[ct], 0.f);
                            *(f32x4*)&dstF[(long)co*sC + (long)od*sD + (long)(oh - dst_h0)*sH + ow] = r;
                        }
                    }
                }
            }
        }
    } else {
        // bf16 hi/lo planes (conv2), bn2+relu fused; rows sequential via LDS
        __syncthreads();      // done reading sA (overlay!)
        #pragma unroll
        for (int oi = 0; oi < 2; ++oi) {
            int oh = oh0 + oi;
            bool rv = ((unsigned)oh < (unsigned)GH) && (by*2 + oi < nrows);
            if (rv) {          // block-uniform
                #pragma unroll
                for (int mt = 0; mt < 2; ++mt)
                    #pragma unroll
                    for (int ct = 0; ct < 2; ++ct) {
                        int co = (cth*2 + ct)*16 + wl;
                        #pragma unroll
                        for (int e = 0; e < 4; ++e) {
                            int owl = (mh*2 + mt)*16 + kg*4 + e;
                            sOut[owl*68 + co] = fmaxf(acc[oi][mt][ct][e]*so[ct] + bo[ct], 0.f);
                        }
                    }
                __syncthreads();
                for (int f = t; f < 1024; f += 256) {
                    int w = f >> 4, c4 = f & 15;
                    if (w0 + w < GW) {
                        float4 v = *(const float4*)&sOut[w*68 + c4*4];
                        long base = (long)od*sD + (long)(oh - dst_h0)*sH + (long)(w0 + w)*64 + c4*4;
                        bf16_t h0 = (bf16_t)v.x, h1 = (bf16_t)v.y, h2 = (bf16_t)v.z, h3 = (bf16_t)v.w;
                        bf16x4 hv; hv[0]=h0; hv[1]=h1; hv[2]=h2; hv[3]=h3;
                        bf16x4 lv;
                        lv[0]=(bf16_t)(v.x-(float)h0); lv[1]=(bf16_t)(v.y-(float)h1);
                        lv[2]=(bf16_t)(v.z-(float)h2); lv[3]=(bf16_t)(v.w-(float)h3);
                        *(bf16x4*)&dstH[base] = hv;
                        *(bf16x4*)&dstL[base] = lv;
                    }
                }
                __syncthreads();
            }
        }
    }
}

// ---------------------------------------------------------------------------
extern "C" void kernel_launch(void* const* d_in, const int* in_sizes, int n_in,
                              void* d_out, int out_size, void* d_ws, size_t ws_size,
                              hipStream_t stream)
{
    const float* feats = (const float*)d_in[0];
    const int*   nvox  = (const int*)d_in[1];
    const int*   coors = (const int*)d_in[2];
    const float* w1  = (const float*)d_in[4];
    const float* g1  = (const float*)d_in[5];
    const float* b1  = (const float*)d_in[6];
    const float* w2  = (const float*)d_in[7];
    const float* g2  = (const float*)d_in[8];
    const float* b2  = (const float*)d_in[9];
    const float* wl  = (const float*)d_in[10];
    const float* gl  = (const float*)d_in[11];
    const float* bl  = (const float*)d_in[12];
    const float* wc1 = (const float*)d_in[13];
    const float* gc1 = (const float*)d_in[14];
    const float* bc1 = (const float*)d_in[15];
    const float* wc2 = (const float*)d_in[16];
    const float* gc2 = (const float*)d_in[17];
    const float* bc2 = (const float*)d_in[18];
    const float* wc3 = (const float*)d_in[19];
    const float* gc3 = (const float*)d_in[20];
    const float* bc3 = (const float*)d_in[21];

    int N = in_sizes[1];            // 20000 voxels

    auto al = [](size_t b) { return (b + 255) & ~(size_t)255; };

    size_t winB = al((size_t)10*GH*GW*4);
    size_t voxB = al((size_t)N*128*4);
    size_t w1B  = al((size_t)27*128*64*4);
    size_t wlB  = al((size_t)128*128*4);
    size_t wpB  = al((size_t)13824*8*2);   // one packed bf16 weight buffer
    int NS = 20;
    const int cand[8] = {1, 2, 4, 5, 8, 10, 16, 20};
    for (int k = 0; k < 8; ++k) {
        int ns = cand[k], sh = 400/ns, ar = sh + 4, xr = sh + 2;
        size_t tot = 2*al((size_t)5*ar*GW*64*2) + 2*al((size_t)3*xr*GW*64*2)
                   + winB + voxB + w1B + wlB + 4*wpB + 4096;
        if (tot + (1<<16) <= ws_size) { NS = ns; break; }
    }
    int SH = 400/NS, AR = SH + 4, XR = SH + 2;

    char* ws = (char*)d_ws;
    size_t off = 0;
    auto alloc = [&](size_t bytes) -> void* {
        void* p = ws + off; off += al(bytes); return p;
    };
    size_t accB = (size_t)5*AR*GW*64*2;    // one bf16 plane
    size_t actB = (size_t)3*XR*GW*64*2;
    bf16_t* accH   = (bf16_t*)alloc(accB);
    bf16_t* accL   = (bf16_t*)alloc(accB);
    bf16_t* actH   = (bf16_t*)alloc(actB);
    bf16_t* actL   = (bf16_t*)alloc(actB);
    int*    winner = (int*)alloc((size_t)10*GH*GW*4);
    float*  voxw   = (float*)alloc((size_t)N*128*4);
    float*  wt1    = (float*)alloc((size_t)27*128*64*4);
    float*  wtl    = (float*)alloc((size_t)128*128*4);
    bf16_t* wp2h   = (bf16_t*)alloc(wpB);
    bf16_t* wp2l   = (bf16_t*)alloc(wpB);
    bf16_t* wp3h   = (bf16_t*)alloc(wpB);
    bf16_t* wp3l   = (bf16_t*)alloc(wpB);
    float*  gact   = (float*)alloc(256*4);

    hipMemsetAsync(winner, 0xFF, (size_t)10*GH*GW*4, stream);

    k_prep_all<<<1037, 256, 0, stream>>>(
        wc1, wt1, wl, wtl, wc2, wp2h, wp2l, wc3, wp3h, wp3l, gc1, bc1, gact);

    k_winner<<<(N + 255)/256, 256, 0, stream>>>(coors, winner, N);
    k_vfe<<<N, 128, 0, stream>>>(feats, nvox, w1, g1, b1, w2, g2, b2,
                                 wtl, gl, bl, voxw);

    for (int s = 0; s < NS; ++s) {
        // conv1 gather + bn1+relu + bf16 split (full coverage, no memset)
        k_gat1<<<11*AR*5, 256, 0, stream>>>(
            (const float4*)voxw, winner, (const float4*)wt1,
            accH, accL, gact, s*SH - 2, AR);
        // conv2 (MFMA, 2 rows/block, T14 prefetch): src acc, dst act planes
        int ny2 = (SH + 2 + 1)/2;
        k_convm<<<6*ny2*3, 256, 0, stream>>>(
            accH, accL, s*SH - 2, (long)AR*GW*64,
            nullptr, actH, actL, s*SH - 1, 0L, (long)XR*GW*64, (long)GW*64,
            wp2h, wp2l, gc2, bc2,
            5, 1, 0, s*SH - 1, SH + 2, ny2);
        // conv3 (MFMA, 2 rows/block, T14 prefetch): src act, dst d_out
        int ny3 = (SH + 1)/2;
        k_convm<<<6*ny3*2, 256, 0, stream>>>(
            actH, actL, s*SH - 1, (long)XR*GW*64,
            (float*)d_out, nullptr, nullptr, 0, (long)2*GH*GW, (long)GH*GW, (long)GW,
            wp3h, wp3l, gc3, bc3,
            3, 2, 1, s*SH, SH, ny3);
    }
}